// Round 1
// baseline (512.617 us; speedup 1.0000x reference)
//
#include <hip/hip_runtime.h>
#include <math.h>

#define NB 2      // batch
#define NN 128    // points
#define NO 12     // orientations
#define NIN 16
#define NH 128
#define NBD 32
#define NL 2
#define NHH 512   // WF*H

__device__ __forceinline__ float gelu_f(float x){
    // jax.nn.gelu approximate=True: 0.5*x*(1+tanh(sqrt(2/pi)*(x+0.044715*x^3)))
    float u = 0.7978845608028654f * (x + 0.044715f * x * x * x);
    float t = 1.0f - 2.0f / (__expf(2.0f * u) + 1.0f);   // tanh(u)
    return 0.5f * x * (1.0f + t);
}

// ---------------------------------------------------------------------------
// k_setup: ori (12x3) + fiber_basis (12x12x32), one block
// ---------------------------------------------------------------------------
__global__ __launch_bounds__(256) void k_setup(const float* __restrict__ W1r,
        const float* __restrict__ b1r, const float* __restrict__ W2r,
        const float* __restrict__ b2r, float* __restrict__ ws_ori,
        float* __restrict__ ws_fiber){
    __shared__ float sori[NO*3];
    __shared__ float shid[NO*NO*NH];   // 73728 B
    int tid = threadIdx.x;
    if (tid < NO){
        float fi = (float)tid;
        float th = fmodf(3.14159265358979323846f * fi * 3.23606797749979f,
                         6.28318530717958647692f);
        float ph = acosf(1.0f - 2.0f*(fi + 0.5f)/12.0f);
        float sp = sinf(ph);
        float ox = sp*cosf(th), oy = sp*sinf(th), oz = cosf(ph);
        sori[tid*3+0]=ox; sori[tid*3+1]=oy; sori[tid*3+2]=oz;
        ws_ori[tid*3+0]=ox; ws_ori[tid*3+1]=oy; ws_ori[tid*3+2]=oz;
    }
    __syncthreads();
    for (int e = tid; e < NO*NO*NH; e += 256){
        int t = e & 127, row = e >> 7;
        int p = row / NO, q = row - p*NO;
        float xv = sori[p*3]*sori[q*3] + sori[p*3+1]*sori[q*3+1] + sori[p*3+2]*sori[q*3+2];
        float acc = b1r[t] + xv*W1r[t] + xv*xv*W1r[NH+t] + xv*xv*xv*W1r[2*NH+t];
        shid[e] = gelu_f(acc);
    }
    __syncthreads();
    for (int e = tid; e < NO*NO*NBD; e += 256){
        int d = e & 31, row = e >> 5;
        float acc = b2r[d];
        const float* hr = shid + row*NH;
        for (int t = 0; t < NH; ++t) acc += hr[t]*W2r[t*NBD + d];
        ws_fiber[e] = gelu_f(acc);
    }
}

// ---------------------------------------------------------------------------
// k_rot: rot[i][p][o][c] = sum_d fiber[p][o][d] * Wrot[i][d][c]
// ---------------------------------------------------------------------------
__global__ __launch_bounds__(256) void k_rot(const float* __restrict__ fiber,
        const float* __restrict__ Wrot, float* __restrict__ rot){
    int g = blockIdx.x*256 + threadIdx.x;      // NL*NO*NO*NH = 36864
    int c = g & 127; int rest = g >> 7;
    int o = rest % NO; rest /= NO;
    int p = rest % NO; int i = rest / NO;
    const float* f = fiber + (p*NO + o)*NBD;
    const float* w = Wrot + (size_t)i*NBD*NH + c;
    float acc = 0.f;
    #pragma unroll
    for (int d = 0; d < NBD; ++d) acc += f[d]*w[d*NH];
    rot[g] = acc;
}

// ---------------------------------------------------------------------------
// k_embed: hA[b][o][n][c] = sum_k x[b,n,k]*We[k,c]   (broadcast over o)
// ---------------------------------------------------------------------------
__global__ __launch_bounds__(256) void k_embed(const float* __restrict__ x,
        const float* __restrict__ We, float* __restrict__ hA){
    int g = blockIdx.x*256 + threadIdx.x;      // NB*NO*NN*NH = 393216
    int c = g & 127; int n = (g >> 7) & 127; int rest = g >> 14;
    int b = rest / NO;
    const float* xp = x + ((size_t)b*NN + n)*NIN;
    float acc = 0.f;
    #pragma unroll
    for (int k = 0; k < NIN; ++k) acc += xp[k]*We[k*NH + c];
    hA[g] = acc;
}

// ---------------------------------------------------------------------------
// k_kb: kernel_basis[b][o][m][n][d], 64 n-rows per block
// ---------------------------------------------------------------------------
__global__ __launch_bounds__(256) void k_kb(const float* __restrict__ pos,
        const float* __restrict__ W1s, const float* __restrict__ b1s,
        const float* __restrict__ W2s, const float* __restrict__ b2s,
        const float* __restrict__ ori, float* __restrict__ kb){
    __shared__ __align__(16) float sW1[14*NH];
    __shared__ float sb1[NH];
    __shared__ __align__(16) float sW2[NH*NBD];
    __shared__ float sb2[NBD];
    __shared__ float spf[64*14];
    __shared__ __align__(16) float shid[64*132];   // padded rows (132 = 4*33)
    int tid = threadIdx.x;
    int bid = blockIdx.x;                 // 6144 = NB*NO*NN*2
    int n0 = (bid & 1)*64;
    int m  = (bid >> 1) & 127;
    int t2 = bid >> 8;                    // 0..23
    int o = t2 % NO, b = t2 / NO;

    for (int e = tid; e < 14*NH;  e += 256) sW1[e] = W1s[e];
    for (int e = tid; e < NH*NBD; e += 256) sW2[e] = W2s[e];
    if (tid < NH)  sb1[tid] = b1s[tid];
    if (tid < NBD) sb2[tid] = b2s[tid];
    if (tid < 64){
        int n = n0 + tid;
        float rx = pos[((size_t)b*NN+n)*3+0] - pos[((size_t)b*NN+m)*3+0];
        float ry = pos[((size_t)b*NN+n)*3+1] - pos[((size_t)b*NN+m)*3+1];
        float rz = pos[((size_t)b*NN+n)*3+2] - pos[((size_t)b*NN+m)*3+2];
        float ox = ori[o*3+0], oy = ori[o*3+1], oz = ori[o*3+2];
        float a  = rx*ox + ry*oy + rz*oz;                          // inv1
        float bb = sqrtf(rx*rx+ry*ry+rz*rz) * fabsf(1.0f - a);    // inv2
        float* p = spf + tid*14;
        p[0]=a;      p[1]=bb;
        p[2]=a*a;    p[3]=a*bb;    p[4]=bb*a;    p[5]=bb*bb;
        p[6]=a*a*a;  p[7]=a*a*bb;  p[8]=a*bb*a;  p[9]=a*bb*bb;
        p[10]=bb*a*a; p[11]=bb*a*bb; p[12]=bb*bb*a; p[13]=bb*bb*bb;
    }
    __syncthreads();
    // hidden: 64 rows x 128
    for (int it = 0; it < 32; ++it){
        int e = it*256 + tid;
        int t = e & 127, r = e >> 7;
        const float* pf = spf + r*14;
        float acc = sb1[t];
        #pragma unroll
        for (int k = 0; k < 14; ++k) acc += pf[k]*sW1[k*NH + t];
        shid[r*132 + t] = gelu_f(acc);
    }
    __syncthreads();
    // out: 64 rows x 32, 2r x 4d tile per thread
    int dg = tid & 7, rr = tid >> 3;
    int r0 = rr*2, d0 = dg*4;
    float4 a0, a1;
    a0.x = a1.x = sb2[d0+0]; a0.y = a1.y = sb2[d0+1];
    a0.z = a1.z = sb2[d0+2]; a0.w = a1.w = sb2[d0+3];
    for (int t4 = 0; t4 < NH; t4 += 4){
        float4 h0 = *(const float4*)&shid[ r0     *132 + t4];
        float4 h1 = *(const float4*)&shid[(r0+1)*132 + t4];
        float4 w0 = *(const float4*)&sW2[(t4+0)*NBD + d0];
        float4 w1 = *(const float4*)&sW2[(t4+1)*NBD + d0];
        float4 w2 = *(const float4*)&sW2[(t4+2)*NBD + d0];
        float4 w3 = *(const float4*)&sW2[(t4+3)*NBD + d0];
        a0.x += h0.x*w0.x + h0.y*w1.x + h0.z*w2.x + h0.w*w3.x;
        a0.y += h0.x*w0.y + h0.y*w1.y + h0.z*w2.y + h0.w*w3.y;
        a0.z += h0.x*w0.z + h0.y*w1.z + h0.z*w2.z + h0.w*w3.z;
        a0.w += h0.x*w0.w + h0.y*w1.w + h0.z*w2.w + h0.w*w3.w;
        a1.x += h1.x*w0.x + h1.y*w1.x + h1.z*w2.x + h1.w*w3.x;
        a1.y += h1.x*w0.y + h1.y*w1.y + h1.z*w2.y + h1.w*w3.y;
        a1.z += h1.x*w0.z + h1.y*w1.z + h1.z*w2.z + h1.w*w3.z;
        a1.w += h1.x*w0.w + h1.y*w1.w + h1.z*w2.w + h1.w*w3.w;
    }
    size_t base = (((size_t)(b*NO + o)*NN + m)*NN + n0)*NBD;
    float4 g0, g1;
    g0.x = gelu_f(a0.x); g0.y = gelu_f(a0.y); g0.z = gelu_f(a0.z); g0.w = gelu_f(a0.w);
    g1.x = gelu_f(a1.x); g1.y = gelu_f(a1.y); g1.z = gelu_f(a1.z); g1.w = gelu_f(a1.w);
    *(float4*)&kb[base +  r0   *NBD + d0] = g0;
    *(float4*)&kb[base + (r0+1)*NBD + d0] = g1;
}

// ---------------------------------------------------------------------------
// k_conv: hOut[b][o][m][c] = sum_n mask[b,n]*hIn[b][o][n][c]*(kb[b,o,m,n,:]·Wsp[:,c])
// block = (b,o,m); Wsp columns in registers; kb row-block in LDS
// ---------------------------------------------------------------------------
__global__ __launch_bounds__(256) void k_conv(const float* __restrict__ hIn,
        const float* __restrict__ kb, const float* __restrict__ wsp_i,
        const float* __restrict__ mask, float* __restrict__ hOut){
    __shared__ __align__(16) float skb[NN*NBD];   // 16 KB
    __shared__ float sred[4*NH];
    int tid = threadIdx.x;
    int bid = blockIdx.x;                 // NB*NO*NN = 3072
    int m = bid & 127; int t = bid >> 7;
    int o = t % NO, b = t / NO;
    const float* kbp = kb + (((size_t)(b*NO + o)*NN + m)*NN)*NBD;
    for (int e = tid; e < NN*NBD/4; e += 256)
        ((float4*)skb)[e] = ((const float4*)kbp)[e];
    int c2 = tid & 63, nq = tid >> 6;
    int c0 = c2*2;
    float2 wsp[NBD];
    #pragma unroll
    for (int d = 0; d < NBD; ++d) wsp[d] = *(const float2*)&wsp_i[d*NH + c0];
    __syncthreads();
    const float* hbase = hIn + ((size_t)(b*NO + o)*NN)*NH;
    const float* mbase = mask + b*NN;
    float acc0 = 0.f, acc1 = 0.f;
    for (int n = nq*32; n < nq*32 + 32; ++n){
        float mk = mbase[n];
        float2 hm = *(const float2*)&hbase[(size_t)n*NH + c0];
        float w0 = 0.f, w1 = 0.f;
        #pragma unroll
        for (int dq = 0; dq < 8; ++dq){
            float4 kv = *(const float4*)&skb[n*NBD + dq*4];
            w0 += kv.x*wsp[dq*4+0].x; w1 += kv.x*wsp[dq*4+0].y;
            w0 += kv.y*wsp[dq*4+1].x; w1 += kv.y*wsp[dq*4+1].y;
            w0 += kv.z*wsp[dq*4+2].x; w1 += kv.z*wsp[dq*4+2].y;
            w0 += kv.w*wsp[dq*4+3].x; w1 += kv.w*wsp[dq*4+3].y;
        }
        acc0 += w0*(hm.x*mk);
        acc1 += w1*(hm.y*mk);
    }
    sred[nq*NH + c0]     = acc0;
    sred[nq*NH + c0 + 1] = acc1;
    __syncthreads();
    if (tid < NH){
        float v = sred[tid] + sred[NH+tid] + sred[2*NH+tid] + sred[3*NH+tid];
        hOut[(((size_t)(b*NO + o)*NN) + m)*NH + tid] = v;
    }
}

// ---------------------------------------------------------------------------
// k_mlp: rot-mix + conv bias + LN + MLP(128->512->128) + residual. block=(b,m)
// ---------------------------------------------------------------------------
__global__ __launch_bounds__(512) void k_mlp(const float* __restrict__ hConv,
        const float* __restrict__ hIn, float* __restrict__ hOut,
        const float* __restrict__ rot_i, const float* __restrict__ convb_i,
        const float* __restrict__ lns_i, const float* __restrict__ lnb_i,
        const float* __restrict__ Wl1_i, const float* __restrict__ bl1_i,
        const float* __restrict__ Wl2_i, const float* __restrict__ bl2_i){
    __shared__ float shcv[NO*NH];
    __shared__ float sy[NO*NH];
    __shared__ float sU[NO*NHH];
    __shared__ float sred[4*NO*NH];
    int tid = threadIdx.x;
    int bid = blockIdx.x;                 // NB*NN = 256
    int m = bid & 127, b = bid >> 7;
    for (int e = tid; e < NO*NH; e += 512){
        int o = e >> 7, c = e & 127;
        shcv[e] = hConv[(((size_t)b*NO + o)*NN + m)*NH + c];
    }
    __syncthreads();
    for (int e = tid; e < NO*NH; e += 512){
        int p = e >> 7, c = e & 127;
        float acc = 0.f;
        #pragma unroll
        for (int o = 0; o < NO; ++o)
            acc += shcv[o*NH + c]*rot_i[(p*NO + o)*NH + c];
        sy[e] = acc*(1.0f/12.0f) + convb_i[c];
    }
    __syncthreads();
    // layernorm per row (over H)
    int wid = tid >> 6, lane = tid & 63;
    for (int row = wid; row < NO; row += 8){
        float x0 = sy[row*NH + lane], x1 = sy[row*NH + 64 + lane];
        float s = x0 + x1, ss = x0*x0 + x1*x1;
        for (int off = 32; off; off >>= 1){
            s  += __shfl_xor(s,  off);
            ss += __shfl_xor(ss, off);
        }
        float mn  = s*(1.0f/128.0f);
        float var = ss*(1.0f/128.0f) - mn*mn;
        float r = rsqrtf(var + 1e-6f);
        sy[row*NH + lane]      = (x0 - mn)*r*lns_i[lane]      + lnb_i[lane];
        sy[row*NH + 64 + lane] = (x1 - mn)*r*lns_i[64 + lane] + lnb_i[64 + lane];
    }
    __syncthreads();
    // MLP layer1: thread j over 512, all 12 rows at once (Wl1 read once)
    {
        int j = tid;
        float acc[NO];
        float bj = bl1_i[j];
        #pragma unroll
        for (int p = 0; p < NO; ++p) acc[p] = bj;
        for (int c = 0; c < NH; ++c){
            float w = Wl1_i[(size_t)c*NHH + j];
            #pragma unroll
            for (int p = 0; p < NO; ++p) acc[p] += sy[p*NH + c]*w;
        }
        #pragma unroll
        for (int p = 0; p < NO; ++p) sU[p*NHH + j] = gelu_f(acc[p]);
    }
    __syncthreads();
    // MLP layer2: (c, j-quarter) split
    {
        int q = tid >> 7, c = tid & 127;
        float acc[NO];
        #pragma unroll
        for (int p = 0; p < NO; ++p) acc[p] = 0.f;
        for (int j = q*128; j < q*128 + 128; ++j){
            float w = Wl2_i[(size_t)j*NH + c];
            #pragma unroll
            for (int p = 0; p < NO; ++p) acc[p] += sU[p*NHH + j]*w;
        }
        #pragma unroll
        for (int p = 0; p < NO; ++p) sred[(q*NO + p)*NH + c] = acc[p];
    }
    __syncthreads();
    for (int e = tid; e < NO*NH; e += 512){
        int p = e >> 7, c = e & 127;
        float v = sred[(0*NO+p)*NH + c] + sred[(1*NO+p)*NH + c]
                + sred[(2*NO+p)*NH + c] + sred[(3*NO+p)*NH + c];
        size_t gi = (((size_t)b*NO + p)*NN + m)*NH + c;
        hOut[gi] = v + bl2_i[c] + hIn[gi];
    }
}

// ---------------------------------------------------------------------------
// k_readout: out[b] = sum_{m,o} mask[b,m]*(h·Wro + bro) / (12 * sum_m mask)
// ---------------------------------------------------------------------------
__global__ __launch_bounds__(256) void k_readout(const float* __restrict__ h,
        const float* __restrict__ Wro, const float* __restrict__ bro,
        const float* __restrict__ mask, float* __restrict__ out){
    __shared__ float sw[NH];
    __shared__ float sacc[4], smsk[4];
    int tid = threadIdx.x, b = blockIdx.x;
    if (tid < NH) sw[tid] = Wro[tid];
    __syncthreads();
    float br = bro[0];
    float acc = 0.f;
    for (int e = tid; e < NN*NO; e += 256){
        int o = e % NO, mm = e / NO;
        const float* hp = h + (((size_t)b*NO + o)*NN + mm)*NH;
        float dot = 0.f;
        for (int c = 0; c < NH; ++c) dot += hp[c]*sw[c];
        acc += (dot + br)*mask[b*NN + mm];
    }
    float msum = (tid < NN) ? mask[b*NN + tid] : 0.f;
    for (int off = 32; off; off >>= 1){
        acc  += __shfl_xor(acc,  off);
        msum += __shfl_xor(msum, off);
    }
    if ((tid & 63) == 0){ sacc[tid>>6] = acc; smsk[tid>>6] = msum; }
    __syncthreads();
    if (tid == 0){
        float a = sacc[0]+sacc[1]+sacc[2]+sacc[3];
        float mm2 = smsk[0]+smsk[1]+smsk[2]+smsk[3];
        out[b] = a/(12.0f*mm2);
    }
}

// ---------------------------------------------------------------------------
extern "C" void kernel_launch(void* const* d_in, const int* in_sizes, int n_in,
                              void* d_out, int out_size, void* d_ws, size_t ws_size,
                              hipStream_t stream){
    const float* pos  = (const float*)d_in[0];
    const float* x    = (const float*)d_in[1];
    const float* mask = (const float*)d_in[2];
    const float* W1s  = (const float*)d_in[3];
    const float* b1s  = (const float*)d_in[4];
    const float* W2s  = (const float*)d_in[5];
    const float* b2s  = (const float*)d_in[6];
    const float* W1r  = (const float*)d_in[7];
    const float* b1r  = (const float*)d_in[8];
    const float* W2r  = (const float*)d_in[9];
    const float* b2r  = (const float*)d_in[10];
    const float* We   = (const float*)d_in[11];
    const float* Wsp  = (const float*)d_in[12];
    const float* Wrot = (const float*)d_in[13];
    const float* convb= (const float*)d_in[14];
    const float* lns  = (const float*)d_in[15];
    const float* lnb  = (const float*)d_in[16];
    const float* Wl1  = (const float*)d_in[17];
    const float* bl1  = (const float*)d_in[18];
    const float* Wl2  = (const float*)d_in[19];
    const float* bl2  = (const float*)d_in[20];
    const float* Wro  = (const float*)d_in[21];
    const float* bro  = (const float*)d_in[22];

    float* ws = (float*)d_ws;
    float* ws_ori = ws;                       // 64 (36 used)
    float* ws_fib = ws + 64;                  // 4608
    float* ws_rot = ws + 64 + 4608;           // NL*NO*NO*NH = 36864
    float* hA = ws_rot + NL*NO*NO*NH;         // 393216 each
    float* hB = hA + NB*NO*NN*NH;
    float* hC = hB + NB*NO*NN*NH;
    float* kb = hC + NB*NO*NN*NH;             // 12582912 floats

    k_setup<<<1, 256, 0, stream>>>(W1r, b1r, W2r, b2r, ws_ori, ws_fib);
    k_rot<<<NL*NO*NO*NH/256, 256, 0, stream>>>(ws_fib, Wrot, ws_rot);
    k_embed<<<NB*NO*NN*NH/256, 256, 0, stream>>>(x, We, hA);
    k_kb<<<NB*NO*NN*2, 256, 0, stream>>>(pos, W1s, b1s, W2s, b2s, ws_ori, kb);

    // layer 0: hA -> (conv) hC -> (mlp, residual hA) -> hB
    k_conv<<<NB*NO*NN, 256, 0, stream>>>(hA, kb, Wsp, mask, hC);
    k_mlp<<<NB*NN, 512, 0, stream>>>(hC, hA, hB,
            ws_rot, convb, lns, lnb,
            Wl1, bl1, Wl2, bl2);
    // layer 1: hB -> hC -> hA
    k_conv<<<NB*NO*NN, 256, 0, stream>>>(hB, kb, Wsp + NBD*NH, mask, hC);
    k_mlp<<<NB*NN, 512, 0, stream>>>(hC, hB, hA,
            ws_rot + NO*NO*NH, convb + NH, lns + NH, lnb + NH,
            Wl1 + NH*NHH, bl1 + NHH, Wl2 + NHH*NH, bl2 + NH);

    k_readout<<<NB, 256, 0, stream>>>(hA, Wro, bro, mask, (float*)d_out);
}